// Round 2
// baseline (311.856 us; speedup 1.0000x reference)
//
#include <hip/hip_runtime.h>

// B=2048, N=64, D=256, H=16.
// out[b,n] = softmax_n( relu( ((N*u[b,n,:] - sum_n u) * item) @ W1 + b1 ) @ W2 )
// b2 dropped (softmax shift-invariant). Identity: y'[n,h]=(u[n,:]*item)@W1[:,h],
// z = 64*y' - sum_n y' + b1.
//
// Round-2 structure: NO u staging in LDS, NO in-loop barriers. Each lane owns a
// private d-subset {d = 16j+4q+e} of 4 member-rows {n0+16k}; u goes straight
// from global (64-B coalesced per 4-lane group) into a 2-chunk register
// pipeline; W1 rows are broadcast from a padded LDS copy (stride 20 floats ->
// 2-way bank alias only, free per m136). Partial y reduced over q via 2
// shuffles; softmax over n0-lanes via xor 4..32. Memory-bound target:
// 137 MB @ 6.3 TB/s ~= 22 us.

static constexpr int NMEM = 64;
static constexpr int DDIM = 256;
static constexpr int HD   = 16;
static constexpr int W1S  = 20;   // padded LDS row stride (floats), 16-B aligned

__global__ __launch_bounds__(256, 2)
void attn_group_softmax(const float* __restrict__ u_g,     // [B,64,256]
                        const float* __restrict__ item_g,  // [B,256]
                        const float* __restrict__ W1,      // [256,16]
                        const float* __restrict__ b1,      // [16]
                        const float* __restrict__ W2,      // [16,1]
                        float* __restrict__ out)           // [B,64]
{
    __shared__ __align__(16) float w1s[DDIM * W1S];   // 20 KB

    const int tid  = threadIdx.x;
    const int w    = tid >> 6;                // wave 0..3
    const int lane = tid & 63;
    const int b    = blockIdx.x * 4 + w;      // one batch per wave

    // ---- stage W1 into LDS, padded (thread tid copies d-row tid) ----
    {
        const float4* src = (const float4*)(W1 + tid * HD);
        float4*       dst = (float4*)(w1s + tid * W1S);
        #pragma unroll
        for (int c = 0; c < 4; ++c) dst[c] = src[c];
    }
    __syncthreads();   // the only barrier in the kernel

    const int q  = lane & 3;    // d-subset selector AND h-partial owner
    const int n0 = lane >> 2;   // 0..15; lane computes rows n0+16k, k=0..3

    const float4* ug4 = (const float4*)u_g + (size_t)b * (NMEM * DDIM / 4);
    const float4* it4 = (const float4*)item_g + (size_t)b * (DDIM / 4);

    float acc[4][16];           // partial y'[row k][h] over this lane's d-subset
    #pragma unroll
    for (int k = 0; k < 4; ++k)
        #pragma unroll
        for (int h = 0; h < 16; ++h) acc[k][h] = 0.f;

    // register pipeline, prefetch distance 2 (chunk j = 16 d-values)
    float4 ub[4][4];
    float4 itb[4];
    #pragma unroll
    for (int jj = 0; jj < 2; ++jj) {
        #pragma unroll
        for (int k = 0; k < 4; ++k)
            ub[jj][k] = ug4[(n0 + 16 * k) * 64 + jj * 4 + q];
        itb[jj] = it4[jj * 4 + q];
    }

    #pragma unroll 4
    for (int j = 0; j < 16; ++j) {
        const int cur = j & 3;
        const int nxt = (j + 2) & 3;
        if (j + 2 < 16) {   // uniform branch; guards OOB on the last batch
            #pragma unroll
            for (int k = 0; k < 4; ++k)
                ub[nxt][k] = ug4[(n0 + 16 * k) * 64 + (j + 2) * 4 + q];
            itb[nxt] = it4[(j + 2) * 4 + q];
        }

        const float4 itv = itb[cur];
        float s[4][4];   // u * item for 4 rows x 4 d-values
        #pragma unroll
        for (int k = 0; k < 4; ++k) {
            s[k][0] = ub[cur][k].x * itv.x;
            s[k][1] = ub[cur][k].y * itv.y;
            s[k][2] = ub[cur][k].z * itv.z;
            s[k][3] = ub[cur][k].w * itv.w;
        }

        #pragma unroll
        for (int e = 0; e < 4; ++e) {
            const int d = 16 * j + 4 * q + e;
            const float4* wrow = (const float4*)(w1s + d * W1S);
            #pragma unroll
            for (int hc = 0; hc < 4; ++hc) {
                const float4 wv = wrow[hc];   // 2-way bank alias max (stride 20)
                #pragma unroll
                for (int k = 0; k < 4; ++k) {
                    acc[k][4 * hc + 0] = fmaf(s[k][e], wv.x, acc[k][4 * hc + 0]);
                    acc[k][4 * hc + 1] = fmaf(s[k][e], wv.y, acc[k][4 * hc + 1]);
                    acc[k][4 * hc + 2] = fmaf(s[k][e], wv.z, acc[k][4 * hc + 2]);
                    acc[k][4 * hc + 3] = fmaf(s[k][e], wv.w, acc[k][4 * hc + 3]);
                }
            }
        }
    }

    // ---- reduce partial d-sums over the 4 q-lanes (xor 1,2) ----
    #pragma unroll
    for (int k = 0; k < 4; ++k)
        #pragma unroll
        for (int h = 0; h < 16; ++h) {
            float v = acc[k][h];
            v += __shfl_xor(v, 1, 64);
            v += __shfl_xor(v, 2, 64);
            acc[k][h] = v;   // full y'[n0+16k][h], replicated across q
        }

    // ---- tt[h] = sum over all 64 members ----
    float tt[16];
    #pragma unroll
    for (int h = 0; h < 16; ++h) {
        float v = acc[0][h] + acc[1][h] + acc[2][h] + acc[3][h];
        #pragma unroll
        for (int off = 4; off <= 32; off <<= 1) v += __shfl_xor(v, off, 64);
        tt[h] = v;
    }

    // ---- b1 / W2 (tiny, L2-resident broadcasts) ----
    float b1c[16], w2c[16];
    {
        const float4* b4 = (const float4*)b1;
        const float4* w4 = (const float4*)W2;
        #pragma unroll
        for (int c = 0; c < 4; ++c) {
            const float4 t1 = b4[c], t2 = w4[c];
            b1c[4*c+0] = t1.x; b1c[4*c+1] = t1.y; b1c[4*c+2] = t1.z; b1c[4*c+3] = t1.w;
            w2c[4*c+0] = t2.x; w2c[4*c+1] = t2.y; w2c[4*c+2] = t2.z; w2c[4*c+3] = t2.w;
        }
    }

    // ---- logits: z = 64*y' - tt + b1, relu, dot W2 ----
    float p[4];
    #pragma unroll
    for (int k = 0; k < 4; ++k) {
        float sum = 0.f;
        #pragma unroll
        for (int h = 0; h < 16; ++h) {
            float z = fmaf(64.f, acc[k][h], b1c[h] - tt[h]);
            z = fmaxf(z, 0.f);
            sum = fmaf(z, w2c[h], sum);
        }
        p[k] = sum;
    }

    // ---- softmax over 64 members (16 n0-lanes x 4 rows, q-replicated) ----
    float m = fmaxf(fmaxf(p[0], p[1]), fmaxf(p[2], p[3]));
    #pragma unroll
    for (int off = 4; off <= 32; off <<= 1) m = fmaxf(m, __shfl_xor(m, off, 64));
    const float e0 = __expf(p[0] - m);
    const float e1 = __expf(p[1] - m);
    const float e2 = __expf(p[2] - m);
    const float e3 = __expf(p[3] - m);
    float sden = e0 + e1 + e2 + e3;
    #pragma unroll
    for (int off = 4; off <= 32; off <<= 1) sden += __shfl_xor(sden, off, 64);
    const float inv = 1.0f / sden;

    if (q == 0) {
        float* ob = out + (size_t)b * NMEM + n0;
        ob[0]  = e0 * inv;
        ob[16] = e1 * inv;
        ob[32] = e2 * inv;
        ob[48] = e3 * inv;
    }
}

extern "C" void kernel_launch(void* const* d_in, const int* in_sizes, int n_in,
                              void* d_out, int out_size, void* d_ws, size_t ws_size,
                              hipStream_t stream) {
    const float* u    = (const float*)d_in[0];  // members_embeds [2048,64,256]
    const float* item = (const float*)d_in[1];  // item_embeds   [2048,256]
    const float* W1   = (const float*)d_in[2];  // [256,16]
    const float* b1   = (const float*)d_in[3];  // [16]
    const float* W2   = (const float*)d_in[4];  // [16,1]
    // d_in[5] = b2: dropped (softmax shift-invariant)
    (void)in_sizes; (void)n_in; (void)out_size; (void)d_ws; (void)ws_size;

    attn_group_softmax<<<512, 256, 0, stream>>>(u, item, W1, b1, W2, (float*)d_out);
}

// Round 3
// 205.005 us; speedup vs baseline: 1.5212x; 1.5212x over previous
//
#include <hip/hip_runtime.h>

// B=2048, N=64, D=256, H=16.
// out[b,n] = softmax_n( relu( ((N*u[b,n,:] - sum_n u) * item) @ W1 + b1 ) @ W2 )
// b2 dropped (softmax shift-invariant). y'[n,h]=(u[n,:]*item)@W1[:,h];
// z = 64*y' - sum_n y' + b1.
//
// Round-3: same dataflow as round-2 (one wave per batch, lane=(n0,q), no
// in-loop barriers) with the two counter-driven fixes:
//  1. amdgpu_waves_per_eu(2,2): round-2 spilled ~300 MB to scratch because the
//     allocator targeted 4 waves/EU (128 VGPRs) despite needing ~180. Pinning
//     2 waves/EU gives a 256-VGPR budget -> no spill.
//  2. Full-128B-line u reads: lane (n0,q) reads float4 pair 8m+2q{,+1}; each
//     4-lane q-group covers one whole 128-B line, consumed immediately.
//     W1 lives in LDS xor-swizzled (slot c^q) -> q-split reads conflict-free.

static constexpr int NMEM = 64;
static constexpr int DDIM = 256;

__global__ __launch_bounds__(256) __attribute__((amdgpu_waves_per_eu(2, 2)))
void attn_group_softmax(const float* __restrict__ u_g,     // [B,64,256]
                        const float* __restrict__ item_g,  // [B,256]
                        const float* __restrict__ W1,      // [256,16]
                        const float* __restrict__ b1,      // [16]
                        const float* __restrict__ W2,      // [16,1]
                        float* __restrict__ out)           // [B,64]
{
    __shared__ __align__(16) float w1s[DDIM * 16];   // 16 KB, xor-swizzled

    const int tid  = threadIdx.x;
    const int w    = tid >> 6;                // wave 0..3
    const int lane = tid & 63;
    const int b    = blockIdx.x * 4 + w;      // one batch per wave

    // ---- stage W1 swizzled: row d, logical float4 c at physical slot c^((d>>3)&3) ----
    {
        const int d = tid;                    // 256 threads = 256 rows
        const float4* src = (const float4*)(W1 + d * 16);
        float4*       dst = (float4*)w1s + d * 4;
        const int sw = (d >> 3) & 3;
        #pragma unroll
        for (int c = 0; c < 4; ++c) dst[c ^ sw] = src[c];
    }
    __syncthreads();   // the only barrier

    const int q  = lane & 3;    // d-subset selector AND h-partial owner
    const int n0 = lane >> 2;   // 0..15; lane computes rows n0+16k

    const float4* ug4  = (const float4*)u_g + (size_t)b * (NMEM * DDIM / 4);
    const float4* it4  = (const float4*)item_g + (size_t)b * (DDIM / 4);
    const float4* w1s4 = (const float4*)w1s;

    float acc[4][16];
    #pragma unroll
    for (int k = 0; k < 4; ++k)
        #pragma unroll
        for (int h = 0; h < 16; ++h) acc[k][h] = 0.f;

    // double-buffered register pipeline; chunk m = 32 d-values, lane owns
    // d = 32m + 8q + e (e=0..7) as two consecutive float4s.
    float4 ub[2][4][2];
    float4 itb[2][2];
    #pragma unroll
    for (int k = 0; k < 4; ++k) {
        ub[0][k][0] = ug4[(n0 + 16 * k) * 64 + 2 * q + 0];
        ub[0][k][1] = ug4[(n0 + 16 * k) * 64 + 2 * q + 1];
    }
    itb[0][0] = it4[2 * q + 0];
    itb[0][1] = it4[2 * q + 1];

    #pragma unroll
    for (int m = 0; m < 8; ++m) {
        const int cur = m & 1, nxt = cur ^ 1;
        if (m < 7) {
            const int base = 8 * (m + 1) + 2 * q;
            #pragma unroll
            for (int k = 0; k < 4; ++k) {
                ub[nxt][k][0] = ug4[(n0 + 16 * k) * 64 + base + 0];
                ub[nxt][k][1] = ug4[(n0 + 16 * k) * 64 + base + 1];
            }
            itb[nxt][0] = it4[base + 0];
            itb[nxt][1] = it4[base + 1];
        }

        // s = u * item for this lane's 8 d-values x 4 rows
        float s[4][8];
        #pragma unroll
        for (int k = 0; k < 4; ++k) {
            s[k][0] = ub[cur][k][0].x * itb[cur][0].x;
            s[k][1] = ub[cur][k][0].y * itb[cur][0].y;
            s[k][2] = ub[cur][k][0].z * itb[cur][0].z;
            s[k][3] = ub[cur][k][0].w * itb[cur][0].w;
            s[k][4] = ub[cur][k][1].x * itb[cur][1].x;
            s[k][5] = ub[cur][k][1].y * itb[cur][1].y;
            s[k][6] = ub[cur][k][1].z * itb[cur][1].z;
            s[k][7] = ub[cur][k][1].w * itb[cur][1].w;
        }

        #pragma unroll
        for (int e = 0; e < 8; ++e) {
            const int d = 32 * m + 8 * q + e;
            const float4* wrow = w1s4 + d * 4;
            float4 wv0 = wrow[0 ^ q];   // logical c=0..3; swizzle (d>>3)&3 == q here
            float4 wv1 = wrow[1 ^ q];
            float4 wv2 = wrow[2 ^ q];
            float4 wv3 = wrow[3 ^ q];
            #pragma unroll
            for (int k = 0; k < 4; ++k) {
                const float sv = s[k][e];
                acc[k][ 0] = fmaf(sv, wv0.x, acc[k][ 0]);
                acc[k][ 1] = fmaf(sv, wv0.y, acc[k][ 1]);
                acc[k][ 2] = fmaf(sv, wv0.z, acc[k][ 2]);
                acc[k][ 3] = fmaf(sv, wv0.w, acc[k][ 3]);
                acc[k][ 4] = fmaf(sv, wv1.x, acc[k][ 4]);
                acc[k][ 5] = fmaf(sv, wv1.y, acc[k][ 5]);
                acc[k][ 6] = fmaf(sv, wv1.z, acc[k][ 6]);
                acc[k][ 7] = fmaf(sv, wv1.w, acc[k][ 7]);
                acc[k][ 8] = fmaf(sv, wv2.x, acc[k][ 8]);
                acc[k][ 9] = fmaf(sv, wv2.y, acc[k][ 9]);
                acc[k][10] = fmaf(sv, wv2.z, acc[k][10]);
                acc[k][11] = fmaf(sv, wv2.w, acc[k][11]);
                acc[k][12] = fmaf(sv, wv3.x, acc[k][12]);
                acc[k][13] = fmaf(sv, wv3.y, acc[k][13]);
                acc[k][14] = fmaf(sv, wv3.z, acc[k][14]);
                acc[k][15] = fmaf(sv, wv3.w, acc[k][15]);
            }
        }
    }

    // ---- reduce partial d-sums over the 4 q-lanes (xor 1,2) ----
    #pragma unroll
    for (int k = 0; k < 4; ++k)
        #pragma unroll
        for (int h = 0; h < 16; ++h) {
            float v = acc[k][h];
            v += __shfl_xor(v, 1, 64);
            v += __shfl_xor(v, 2, 64);
            acc[k][h] = v;   // full y'[n0+16k][h], replicated across q
        }

    // ---- tt[h] = sum over all 64 members ----
    float tt[16];
    #pragma unroll
    for (int h = 0; h < 16; ++h) {
        float v = acc[0][h] + acc[1][h] + acc[2][h] + acc[3][h];
        #pragma unroll
        for (int off = 4; off <= 32; off <<= 1) v += __shfl_xor(v, off, 64);
        tt[h] = v;
    }

    // ---- b1 / W2 ----
    float b1c[16], w2c[16];
    {
        const float4* b4 = (const float4*)b1;
        const float4* w4 = (const float4*)W2;
        #pragma unroll
        for (int c = 0; c < 4; ++c) {
            const float4 t1 = b4[c], t2 = w4[c];
            b1c[4*c+0] = t1.x; b1c[4*c+1] = t1.y; b1c[4*c+2] = t1.z; b1c[4*c+3] = t1.w;
            w2c[4*c+0] = t2.x; w2c[4*c+1] = t2.y; w2c[4*c+2] = t2.z; w2c[4*c+3] = t2.w;
        }
    }

    // ---- logits: z = 64*y' - tt + b1, relu, dot W2 ----
    float p[4];
    #pragma unroll
    for (int k = 0; k < 4; ++k) {
        float sum = 0.f;
        #pragma unroll
        for (int h = 0; h < 16; ++h) {
            float z = fmaf(64.f, acc[k][h], b1c[h] - tt[h]);
            z = fmaxf(z, 0.f);
            sum = fmaf(z, w2c[h], sum);
        }
        p[k] = sum;
    }

    // ---- softmax over 64 members (16 n0-lanes x 4 rows, q-replicated) ----
    float m = fmaxf(fmaxf(p[0], p[1]), fmaxf(p[2], p[3]));
    #pragma unroll
    for (int off = 4; off <= 32; off <<= 1) m = fmaxf(m, __shfl_xor(m, off, 64));
    const float e0 = __expf(p[0] - m);
    const float e1 = __expf(p[1] - m);
    const float e2 = __expf(p[2] - m);
    const float e3 = __expf(p[3] - m);
    float sden = e0 + e1 + e2 + e3;
    #pragma unroll
    for (int off = 4; off <= 32; off <<= 1) sden += __shfl_xor(sden, off, 64);
    const float inv = 1.0f / sden;

    if (q == 0) {
        float* ob = out + (size_t)b * NMEM + n0;
        ob[0]  = e0 * inv;
        ob[16] = e1 * inv;
        ob[32] = e2 * inv;
        ob[48] = e3 * inv;
    }
}

extern "C" void kernel_launch(void* const* d_in, const int* in_sizes, int n_in,
                              void* d_out, int out_size, void* d_ws, size_t ws_size,
                              hipStream_t stream) {
    const float* u    = (const float*)d_in[0];  // members_embeds [2048,64,256]
    const float* item = (const float*)d_in[1];  // item_embeds   [2048,256]
    const float* W1   = (const float*)d_in[2];  // [256,16]
    const float* b1   = (const float*)d_in[3];  // [16]
    const float* W2   = (const float*)d_in[4];  // [16,1]
    // d_in[5] = b2: dropped (softmax shift-invariant)
    (void)in_sizes; (void)n_in; (void)out_size; (void)d_ws; (void)ws_size;

    attn_group_softmax<<<512, 256, 0, stream>>>(u, item, W1, b1, W2, (float*)d_out);
}